// Round 2
// baseline (264.414 us; speedup 1.0000x reference)
//
#include <hip/hip_runtime.h>
#include <hip/hip_bf16.h>
#include <cstdint>
#include <cstddef>

// MFMA fragment types (gfx950: V8y operands, V4f accumulator)
typedef __bf16 v8bf __attribute__((ext_vector_type(8)));
typedef float  v4f  __attribute__((ext_vector_type(4)));

__device__ __forceinline__ unsigned short f2bf(float f) {
    unsigned int u = __float_as_uint(f);
    u += 0x7fffu + ((u >> 16) & 1u);   // round-to-nearest-even
    return (unsigned short)(u >> 16);
}

// async global->LDS, 16B per lane. LDS deposit is wave-uniform base + lane*16.
__device__ __forceinline__ void gload_lds16(const unsigned short* g, unsigned short* l) {
    __builtin_amdgcn_global_load_lds(
        (const __attribute__((address_space(1))) unsigned int*)(uintptr_t)g,
        (__attribute__((address_space(3))) unsigned int*)(uintptr_t)l, 16, 0, 0);
}

// ---------------------------------------------------------------------------
// Legacy 128x128 GEMM (kept only for the small Wfold GEMM, 128 blocks).
// C[M,N] = A[M,K] * B[K,N], B transposed (BT is N x K). bf16 in, fp32 acc.
// ---------------------------------------------------------------------------
template<int WRITE_BF16>
__global__ __launch_bounds__(256, 2) void gemm_bt(
    const unsigned short* __restrict__ A,   // M x K, row stride lda (bf16)
    const unsigned short* __restrict__ BT,  // N x K, row stride ldb (bf16)
    void* __restrict__ C,                   // M x N, row stride ldc
    int K, int lda, int ldb, int ldc,
    size_t sAz, size_t sBz, size_t sCz,     // per-z strides (elements)
    int nBlk, int mPerXcd)
{
    __shared__ unsigned short sA[128 * 32];
    __shared__ unsigned short sB[128 * 32];

    const int id = blockIdx.x;
    const int xcd = id & 7;
    int s = id >> 3;
    const int perXcd = mPerXcd * nBlk;
    const int z = s / perXcd;
    s -= z * perXcd;
    const int mB = xcd * mPerXcd + s / nBlk;
    const int nB = s - (s / nBlk) * nBlk;

    const unsigned short* Ab = A + (size_t)z * sAz;
    const unsigned short* Bb = BT + (size_t)z * sBz;

    const int tid  = threadIdx.x;
    const int wv   = tid >> 6;
    const int lane = tid & 63;
    const int quad = lane >> 4;
    const int l16  = lane & 15;
    const size_t bm = (size_t)mB * 128;
    const size_t bn = (size_t)nB * 128;
    const int wm = (wv >> 1) * 64;
    const int wn = (wv & 1) * 64;

    const int ro = tid >> 2;
    const int ko = (((tid & 3) ^ (ro & 3)) << 3);

    const unsigned short* aptr0 = Ab + (bm + ro)      * (size_t)lda + ko;
    const unsigned short* aptr1 = Ab + (bm + ro + 64) * (size_t)lda + ko;
    const unsigned short* bptr0 = Bb + (bn + ro)      * (size_t)ldb + ko;
    const unsigned short* bptr1 = Bb + (bn + ro + 64) * (size_t)ldb + ko;

    unsigned short* sA0 = &sA[wv * 512];
    unsigned short* sA1 = &sA[2048 + wv * 512];
    unsigned short* sB0 = &sB[wv * 512];
    unsigned short* sB1 = &sB[2048 + wv * 512];

    const int sslot = ((quad ^ (l16 & 3)) << 3);

    v4f acc[4][4] = {};

    for (int k0 = 0; k0 < K; k0 += 32) {
        gload_lds16(aptr0 + k0, sA0);
        gload_lds16(aptr1 + k0, sA1);
        gload_lds16(bptr0 + k0, sB0);
        gload_lds16(bptr1 + k0, sB1);
        __syncthreads();

        v8bf af[4], bfr[4];
        #pragma unroll
        for (int t = 0; t < 4; t++) {
            af[t]  = *(const v8bf*)&sA[(size_t)(wm + t * 16 + l16) * 32 + sslot];
            bfr[t] = *(const v8bf*)&sB[(size_t)(wn + t * 16 + l16) * 32 + sslot];
        }

        #pragma unroll
        for (int ti = 0; ti < 4; ti++)
            #pragma unroll
            for (int tj = 0; tj < 4; tj++)
                acc[ti][tj] = __builtin_amdgcn_mfma_f32_16x16x32_bf16(
                    af[ti], bfr[tj], acc[ti][tj], 0, 0, 0);
        __syncthreads();
    }

    if (WRITE_BF16) {
        unsigned short* Cb = (unsigned short*)C + (size_t)z * sCz;
        #pragma unroll
        for (int ti = 0; ti < 4; ti++) {
            const size_t row0 = bm + wm + ti * 16 + quad * 4;
            #pragma unroll
            for (int tj = 0; tj < 4; tj++) {
                const size_t col = bn + wn + tj * 16 + l16;
                #pragma unroll
                for (int r = 0; r < 4; r++)
                    Cb[(row0 + r) * (size_t)ldc + col] = f2bf(acc[ti][tj][r]);
            }
        }
    } else {
        float* Cb = (float*)C + (size_t)z * sCz;
        #pragma unroll
        for (int ti = 0; ti < 4; ti++) {
            const size_t row0 = bm + wm + ti * 16 + quad * 4;
            #pragma unroll
            for (int tj = 0; tj < 4; tj++) {
                const size_t col = bn + wn + tj * 16 + l16;
                #pragma unroll
                for (int r = 0; r < 4; r++)
                    Cb[(row0 + r) * (size_t)ldc + col] = acc[ti][tj][r];
            }
        }
    }
}

// ---------------------------------------------------------------------------
// 256x256-tile, BK=64, 8-wave (2Mx4N), 8-phase GEMM, counted vmcnt (T2+T3+T4+T5).
// Round-2 changes vs round-1 port (which stalled at MfmaUtil 29%):
//  * 2 K-tiles per loop iteration -> compile-time LDS buffer bases.
//  * Balanced 8/4/8/4 ds_read phases: B(nh0) of tile t+1 is read in tile t's
//    ph4 AFTER the counted vmcnt(6) (which guarantees all of t+1 has landed),
//    into the alternate register bank b0a/b0b. ph1 is now an 8-read burst.
//  * sched_barrier(0) after every inline lgkmcnt(0) (rule 18) so the
//    scheduler cannot deform the phase structure.
//  * compiler "memory" pin after the ph4 early-read so it can't sink.
// Phase map per K-tile t (P = t&1, steady state):
//   ph1: rd A(mh0) x8            ; stage A1(t+1)->buf P^1 ; bar;lgkm0;SB; MFMA(0,0)[b0cur]; bar
//   ph2: rd B(nh1) x4            ; stage A0(t+2)->buf P   ; bar;lgkm0;SB; MFMA(0,1)[b1]  ; bar
//   ph3: rd A(mh1) x8            ; stage B0(t+2)->buf P   ; bar;lgkm0;SB; MFMA(1,1)[b1]  ; bar
//   ph4: stage B1(t+2); vmcnt(6) ; rd B0(t+1) x4 -> b0nxt ; bar;          MFMA(1,0)[b0cur]; bar
// vmcnt(6) keeps exactly {A0,B0,B1}(t+2) in flight -> tile t+1 fully landed
// before its B0 read here and its A reads next ph1.  Region overwrite-safety:
// every region's last ds_read drains at that phase's lgkm0 and the closing
// barrier globalizes it before any wave can issue the re-stage.  NT even, >=2.
// ---------------------------------------------------------------------------
#define MFMA_Q(MH, NH, BF)                                                    \
    do {                                                                      \
        __builtin_amdgcn_s_setprio(1);                                        \
        _Pragma("unroll")                                                     \
        for (int mi = 0; mi < 4; ++mi) {                                      \
            _Pragma("unroll")                                                 \
            for (int ni = 0; ni < 2; ++ni) {                                  \
                acc[(MH)*4 + mi][(NH)*2 + ni] =                               \
                    __builtin_amdgcn_mfma_f32_16x16x32_bf16(                  \
                        aF[mi][0], BF[ni][0],                                 \
                        acc[(MH)*4 + mi][(NH)*2 + ni], 0, 0, 0);              \
                acc[(MH)*4 + mi][(NH)*2 + ni] =                               \
                    __builtin_amdgcn_mfma_f32_16x16x32_bf16(                  \
                        aF[mi][1], BF[ni][1],                                 \
                        acc[(MH)*4 + mi][(NH)*2 + ni], 0, 0, 0);              \
            }                                                                 \
        }                                                                     \
        __builtin_amdgcn_s_setprio(0);                                        \
    } while (0)

#define RD_A(BASE)                                                            \
    do {                                                                      \
        _Pragma("unroll")                                                     \
        for (int mi = 0; mi < 4; ++mi) {                                      \
            aF[mi][0] = *(const v8bf*)((BASE) + (arow0 + mi * 1024));         \
            aF[mi][1] = *(const v8bf*)((BASE) + ((arow0 + mi * 1024) ^ 32));  \
        }                                                                     \
    } while (0)

#define RD_B(DST, BASE)                                                       \
    do {                                                                      \
        _Pragma("unroll")                                                     \
        for (int ni = 0; ni < 2; ++ni) {                                      \
            DST[ni][0] = *(const v8bf*)((BASE) + (brow0 + ni * 1024));        \
            DST[ni][1] = *(const v8bf*)((BASE) + ((brow0 + ni * 1024) ^ 32)); \
        }                                                                     \
    } while (0)

#define GTILE(T, P, B0CUR, B0NXT)                                             \
    do {                                                                      \
        const unsigned short* sa = sm + (P) * 16384;                          \
        const unsigned short* sb = sm + 32768 + (P) * 16384;                  \
        unsigned short* dq = sm + ((P) ^ 1) * 16384;                          \
        unsigned short* dp = sm + (P) * 16384;                                \
        const int kk1 = ((T) + 1) * 64, kk2 = ((T) + 2) * 64;                 \
        /* ---- phase 1 ---- */                                               \
        RD_A(sa);                                                             \
        if ((T) + 1 < NT) {                                                   \
            gload_lds16(aP + 128 * lda + kk1, dq + 8192 + stA);               \
            gload_lds16(aP + 192 * lda + kk1, dq + 8192 + stA + 4096);        \
        }                                                                     \
        __builtin_amdgcn_s_barrier();                                         \
        asm volatile("s_waitcnt lgkmcnt(0)" ::: "memory");                    \
        __builtin_amdgcn_sched_barrier(0);                                    \
        MFMA_Q(0, 0, B0CUR);                                                  \
        __builtin_amdgcn_s_barrier();                                         \
        /* ---- phase 2 ---- */                                               \
        RD_B(b1, sb + 8192);                                                  \
        if ((T) + 2 < NT) {                                                   \
            gload_lds16(aP + kk2,            dp + stA);                       \
            gload_lds16(aP + 64 * lda + kk2, dp + stA + 4096);                \
        }                                                                     \
        __builtin_amdgcn_s_barrier();                                         \
        asm volatile("s_waitcnt lgkmcnt(0)" ::: "memory");                    \
        __builtin_amdgcn_sched_barrier(0);                                    \
        MFMA_Q(0, 1, b1);                                                     \
        __builtin_amdgcn_s_barrier();                                         \
        /* ---- phase 3 ---- */                                               \
        RD_A(sa + 8192);                                                      \
        if ((T) + 2 < NT) {                                                   \
            gload_lds16(bP + kk2,            dp + 32768 + stA);               \
            gload_lds16(bP + 64 * ldb + kk2, dp + 32768 + stA + 4096);        \
        }                                                                     \
        __builtin_amdgcn_s_barrier();                                         \
        asm volatile("s_waitcnt lgkmcnt(0)" ::: "memory");                    \
        __builtin_amdgcn_sched_barrier(0);                                    \
        MFMA_Q(1, 1, b1);                                                     \
        __builtin_amdgcn_s_barrier();                                         \
        /* ---- phase 4 ---- */                                               \
        if ((T) + 2 < NT) {                                                   \
            gload_lds16(bP + 128 * ldb + kk2, dp + 32768 + 8192 + stA);       \
            gload_lds16(bP + 192 * ldb + kk2, dp + 32768 + 8192 + stA + 4096);\
            asm volatile("s_waitcnt vmcnt(6)" ::: "memory");                  \
        } else {                                                              \
            asm volatile("s_waitcnt vmcnt(0)" ::: "memory");                  \
        }                                                                     \
        if ((T) + 1 < NT) {                                                   \
            RD_B(B0NXT, sm + 32768 + ((P) ^ 1) * 16384);                      \
            asm volatile("" ::: "memory");                                    \
        }                                                                     \
        __builtin_amdgcn_s_barrier();                                         \
        MFMA_Q(1, 0, B0CUR);                                                  \
        __builtin_amdgcn_s_barrier();                                         \
    } while (0)

template<int WRITE_BF16>
__global__ __launch_bounds__(512, 2) void gemm256_bt(
    const unsigned short* __restrict__ A,   // M x K (bf16), row stride lda
    const unsigned short* __restrict__ BT,  // N x K (bf16), row stride ldb
    void* __restrict__ C,                   // M x N, row stride ldc
    int K, int lda, int ldb, int ldc,
    size_t sAz, size_t sBz, size_t sCz,
    int nBlk, int mPerXcd)
{
    __shared__ unsigned short sm[65536];    // 128 KiB: [A|B][buf][half][128][64]

    const int id = blockIdx.x;
    const int xcd = id & 7;
    int s = id >> 3;
    const int perXcd = mPerXcd * nBlk;
    const int z = s / perXcd;
    s -= z * perXcd;
    const int mB = xcd * mPerXcd + s / nBlk;
    const int nB = s - (s / nBlk) * nBlk;

    const unsigned short* Ab = A + (size_t)z * sAz;
    const unsigned short* Bb = BT + (size_t)z * sBz;

    const int tid  = threadIdx.x;
    const int wv   = tid >> 6;
    const int lane = tid & 63;
    const int quad = lane >> 4;
    const int l16  = lane & 15;
    const int wm   = wv >> 2;               // 0..1
    const int wn   = wv & 3;                // 0..3

    const size_t bm = (size_t)mB * 256;
    const size_t bn = (size_t)nB * 256;

    // staging source (per thread): within-half row r0 = tid>>3, logical 16B
    // slot slog = phys_slot ^ (row&7)  (phys slot = tid&7, row&7 == r0&7)
    const int r0   = tid >> 3;
    const int slog = (tid & 7) ^ (r0 & 7);
    const unsigned short* aP = Ab + (bm + r0) * (size_t)lda + slog * 8;
    const unsigned short* bP = Bb + (bn + r0) * (size_t)ldb + slog * 8;

    // stage dest (shorts, within half): wave-uniform base wv*512; j=1: +4096
    const int stA = wv * 512;

    // ds_read offsets (shorts): phys slot = (ks*4+quad) ^ (l16&7);
    // ks=1 slot = ks=0 slot ^ 4  ->  "^ 32" on the short offset.
    const int soff0 = (quad ^ (l16 & 7)) * 8;
    const int arow0 = (wm * 64 + l16) * 64 + soff0;
    const int brow0 = (wn * 32 + l16) * 64 + soff0;

    v4f  acc[8][4] = {};
    v8bf aF[4][2];          // A frags of current quadrant's M-half
    v8bf b1[2][2];          // B(nh1) of current tile
    v8bf b0a[2][2];         // B(nh0), even tiles
    v8bf b0b[2][2];         // B(nh0), odd tiles

    const int NT = K >> 6;  // even, >= 2

    // ---- prologue: stage tile0 (all 4 halves) + tile1 (A0,B0,B1) ----
    {
        gload_lds16(aP,                sm + stA);
        gload_lds16(aP + 64 * lda,     sm + stA + 4096);
        gload_lds16(aP + 128 * lda,    sm + 8192 + stA);
        gload_lds16(aP + 192 * lda,    sm + 8192 + stA + 4096);
        gload_lds16(bP,                sm + 32768 + stA);
        gload_lds16(bP + 64 * ldb,     sm + 32768 + stA + 4096);
        gload_lds16(bP + 128 * ldb,    sm + 32768 + 8192 + stA);
        gload_lds16(bP + 192 * ldb,    sm + 32768 + 8192 + stA + 4096);
        gload_lds16(aP + 64,                 sm + 16384 + stA);
        gload_lds16(aP + 64 * lda + 64,      sm + 16384 + stA + 4096);
        gload_lds16(bP + 64,                 sm + 32768 + 16384 + stA);
        gload_lds16(bP + 64 * ldb + 64,      sm + 32768 + 16384 + stA + 4096);
        gload_lds16(bP + 128 * ldb + 64,     sm + 32768 + 16384 + 8192 + stA);
        gload_lds16(bP + 192 * ldb + 64,     sm + 32768 + 16384 + 8192 + stA + 4096);
        asm volatile("s_waitcnt vmcnt(6)" ::: "memory");   // tile0 landed
        __builtin_amdgcn_s_barrier();
        RD_B(b0a, sm + 32768);        // B0(tile0); drained by ph1's lgkm0
        asm volatile("" ::: "memory");
    }

    for (int it = 0; it < (NT >> 1); ++it) {
        const int t0 = it * 2;
        GTILE(t0,     0, b0a, b0b);
        GTILE(t0 + 1, 1, b0b, b0a);
    }

    // ---- epilogue ----
    if (WRITE_BF16) {
        unsigned short* Cb = (unsigned short*)C + (size_t)z * sCz;
        #pragma unroll
        for (int mh = 0; mh < 2; ++mh)
            #pragma unroll
            for (int mi = 0; mi < 4; ++mi) {
                const size_t row0 = bm + mh * 128 + wm * 64 + mi * 16 + quad * 4;
                #pragma unroll
                for (int nh = 0; nh < 2; ++nh)
                    #pragma unroll
                    for (int ni = 0; ni < 2; ++ni) {
                        const size_t col = bn + nh * 128 + wn * 32 + ni * 16 + l16;
                        #pragma unroll
                        for (int r = 0; r < 4; ++r)
                            Cb[(row0 + r) * (size_t)ldc + col] =
                                f2bf(acc[mh * 4 + mi][nh * 2 + ni][r]);
                    }
            }
    } else {
        float* Cb = (float*)C + (size_t)z * sCz;
        #pragma unroll
        for (int mh = 0; mh < 2; ++mh)
            #pragma unroll
            for (int mi = 0; mi < 4; ++mi) {
                const size_t row0 = bm + mh * 128 + wm * 64 + mi * 16 + quad * 4;
                #pragma unroll
                for (int nh = 0; nh < 2; ++nh)
                    #pragma unroll
                    for (int ni = 0; ni < 2; ++ni) {
                        const size_t col = bn + nh * 128 + wn * 32 + ni * 16 + l16;
                        #pragma unroll
                        for (int r = 0; r < 4; ++r)
                            Cb[(row0 + r) * (size_t)ldc + col] =
                                acc[mh * 4 + mi][nh * 2 + ni][r];
                    }
            }
    }
}
#undef GTILE
#undef RD_A
#undef RD_B
#undef MFMA_Q

// ---------------------------------------------------------------------------
// Gram via MFMA: partial[split][bh][c][d] = sum_{n in split} M[n][c]*M[n][d],
// M = qk head slice (tokens x 64 ch), row stride 1024. 16 splits x 512 tokens,
// 4 chunks of 128 with register prefetch across the barrier.
// ---------------------------------------------------------------------------
__global__ __launch_bounds__(256) void gram_kernel(
    const unsigned short* __restrict__ qk,   // 16384 x 1024 bf16
    float* __restrict__ partial)             // [16][32][64][64]
{
    const int bh = blockIdx.x;               // b*16+h
    const int split = blockIdx.y;            // 0..15
    const int b = bh >> 4, h = bh & 15;
    const unsigned short* base = qk + (size_t)b * 8192 * 1024 + (size_t)h * 64;
    const int n0 = split * 512;

    __shared__ unsigned short sMT[64 * 136]; // [ch][tok], stride 136
    const int tid = threadIdx.x;
    const int wv = tid >> 6, lane = tid & 63, quad = lane >> 4, l16 = lane & 15;

    uint4 pre[4];
    #pragma unroll
    for (int i = 0; i < 4; i++) {
        const int ch = tid + i * 256, tok = ch >> 3, co = (ch & 7) << 3;
        pre[i] = *(const uint4*)(base + (size_t)(n0 + tok) * 1024 + co);
    }

    v4f acc[4] = {};

    for (int chunk = 0; chunk < 4; chunk++) {
        __syncthreads();   // previous chunk's LDS reads done
        #pragma unroll
        for (int i = 0; i < 4; i++) {
            const int ch = tid + i * 256, tok = ch >> 3, co = (ch & 7) << 3;
            union { uint4 v; unsigned short s8[8]; } u; u.v = pre[i];
            #pragma unroll
            for (int j = 0; j < 8; j++)
                sMT[(size_t)(co + j) * 136 + tok] = u.s8[j];
        }
        __syncthreads();

        if (chunk < 3) {   // issue next chunk's loads; waitcnt lands next iter
            const int nb = n0 + (chunk + 1) * 128;
            #pragma unroll
            for (int i = 0; i < 4; i++) {
                const int ch = tid + i * 256, tok = ch >> 3, co = (ch & 7) << 3;
                pre[i] = *(const uint4*)(base + (size_t)(nb + tok) * 1024 + co);
            }
        }

        #pragma unroll
        for (int ks = 0; ks < 4; ks++) {
            const int kb = ks * 32 + quad * 8;
            const v8bf a = *(const v8bf*)&sMT[(size_t)(16 * wv + l16) * 136 + kb];
            #pragma unroll
            for (int t = 0; t < 4; t++) {
                const v8bf bb = *(const v8bf*)&sMT[(size_t)(t * 16 + l16) * 136 + kb];
                acc[t] = __builtin_amdgcn_mfma_f32_16x16x32_bf16(a, bb, acc[t], 0, 0, 0);
            }
        }
    }

    float* outp = partial + ((size_t)split * 32 + bh) * 4096;
    #pragma unroll
    for (int t = 0; t < 4; t++)
        #pragma unroll
        for (int r = 0; r < 4; r++)
            outp[(size_t)(16 * wv + quad * 4 + r) * 64 + t * 16 + l16] = acc[t][r];
}

// ---------------------------------------------------------------------------
// Softmax: one wave per (bh, c) row over d (64 lanes). Writes TRANSPOSED
// attnT[bh][d][c] so wefft can load without an LDS transpose.
// ---------------------------------------------------------------------------
__global__ __launch_bounds__(256) void softmax_kernel(
    const float* __restrict__ partial,   // [16][32][4096]
    const float* __restrict__ tau,       // [16]
    float* __restrict__ attnT)           // [32][64(d)][64(c)]
{
    const int gw = (int)((blockIdx.x * 256 + threadIdx.x) >> 6);  // 0..2047
    const int d = threadIdx.x & 63;
    const int bh = gw >> 6;
    const int c = gw & 63;
    const int h = bh & 15;

    float cd = 0.f, cc = 0.f, dd = 0.f;
    #pragma unroll
    for (int s = 0; s < 16; s++) {
        const float* p = partial + ((size_t)s * 32 + bh) * 4096;
        cd += p[c * 64 + d];
        cc += p[c * 65];
        dd += p[d * 65];
    }
    const float INV_SQRT_N = 0.011048543456039806f;  // 1/sqrt(8192)
    const float logit = (2.f * cd - cc - dd) * INV_SQRT_N * tau[h];

    float m = logit;
    #pragma unroll
    for (int off = 32; off > 0; off >>= 1) m = fmaxf(m, __shfl_xor(m, off, 64));
    const float e = __expf(logit - m);
    float sum = e;
    #pragma unroll
    for (int off = 32; off > 0; off >>= 1) sum += __shfl_xor(sum, off, 64);

    attnT[(size_t)bh * 4096 + d * 64 + c] = e / sum;
}

// ---------------------------------------------------------------------------
// WeffT[b][j][h*64+d] = sum_c attn[b,h,c,d] * W_out[h*64+c, j]   (bf16 out)
// ---------------------------------------------------------------------------
__global__ __launch_bounds__(256) void wefft_kernel(
    const float* __restrict__ attnT,      // [32][64(d)][64(c)]
    const float* __restrict__ Wout,       // [1024][1024] fp32
    unsigned short* __restrict__ weffT)   // [2][1024][1024] bf16 (j, i)
{
    const int bh = blockIdx.x;            // 0..31
    const int jg = blockIdx.y;            // 0..15
    const int b = bh >> 4, h = bh & 15;

    __shared__ float sAttT[64][65];       // [d][c]
    __shared__ float sW[64][65];          // [c][j_local]
    const int tid = threadIdx.x;
    const float* ap = attnT + (size_t)bh * 4096;
    const float* wp = Wout + (size_t)(h * 64) * 1024 + jg * 64;
    for (int i = tid; i < 4096; i += 256) {
        const int r = i >> 6, q = i & 63;
        sAttT[r][q] = ap[i];              // already transposed in global
        sW[r][q] = wp[(size_t)r * 1024 + q];
    }
    __syncthreads();

    const int dd0 = (tid >> 4) << 2;
    const int j0  = (tid & 15) << 2;
    float acc[4][4] = {};
    for (int cc = 0; cc < 64; cc++) {
        float av[4], wvv[4];
        #pragma unroll
        for (int i = 0; i < 4; i++) av[i] = sAttT[dd0 + i][cc];
        #pragma unroll
        for (int i = 0; i < 4; i++) wvv[i] = sW[cc][j0 + i];
        #pragma unroll
        for (int i = 0; i < 4; i++)
            #pragma unroll
            for (int j = 0; j < 4; j++)
                acc[i][j] += av[i] * wvv[j];
    }

    unsigned short* op = weffT + ((size_t)b * 1024 + jg * 64) * 1024 + h * 64;
    #pragma unroll
    for (int i = 0; i < 4; i++)
        #pragma unroll
        for (int j = 0; j < 4; j++)
            op[(size_t)(j0 + j) * 1024 + dd0 + i] = f2bf(acc[i][j]);
}

// ---------------------------------------------------------------------------
// Fused conversions: x -> bf16 (16384 blks), Wv -> bf16 (1024 blks),
// Wqk -> transposed bf16 (1024 tile blks). One dispatch.
// ---------------------------------------------------------------------------
__global__ __launch_bounds__(256) void cvt_all_kernel(
    const float* __restrict__ x, const float* __restrict__ Wv,
    const float* __restrict__ Wqk,
    unsigned short* __restrict__ xb, unsigned short* __restrict__ wvb,
    unsigned short* __restrict__ wqkT)
{
    const int bid = blockIdx.x;
    if (bid < 17408) {
        const float* src = (bid < 16384) ? x : Wv;
        unsigned short* dst = (bid < 16384) ? xb : wvb;
        const size_t blk = (bid < 16384) ? bid : (bid - 16384);
        const size_t i = (blk * 256 + threadIdx.x) * 4;
        const float4 v = *(const float4*)(src + i);
        ushort4 o;
        o.x = f2bf(v.x); o.y = f2bf(v.y); o.z = f2bf(v.z); o.w = f2bf(v.w);
        *(ushort4*)(dst + i) = o;
    } else {
        const int t = bid - 17408;
        const int n0 = (t & 31) * 32, k0 = (t >> 5) * 32;
        __shared__ float sT[32][33];
        const int tx = threadIdx.x & 31, ty = threadIdx.x >> 5;
        #pragma unroll
        for (int i = ty; i < 32; i += 8)
            sT[i][tx] = Wqk[(size_t)(k0 + i) * 1024 + n0 + tx];
        __syncthreads();
        #pragma unroll
        for (int i = ty; i < 32; i += 8)
            wqkT[(size_t)(n0 + i) * 1024 + k0 + tx] = f2bf(sT[tx][i]);
    }
}

// ---------------------------------------------------------------------------
extern "C" void kernel_launch(void* const* d_in, const int* in_sizes, int n_in,
                              void* d_out, int out_size, void* d_ws, size_t ws_size,
                              hipStream_t stream)
{
    (void)in_sizes; (void)n_in; (void)out_size; (void)ws_size;
    const float* x    = (const float*)d_in[0];
    const float* Wqk  = (const float*)d_in[1];
    const float* Wv   = (const float*)d_in[2];
    const float* Wout = (const float*)d_in[3];
    const float* tau  = (const float*)d_in[4];

    // out_b = x_b @ (W_v @ Weff_b); v never materialized.
    // ws layout:
    //   xb     : 16384x1024  bf16 (32 MB)
    //   wqkT   : 1024x1024   bf16 ( 2 MB)
    //   wvb    : 1024x1024   bf16 ( 2 MB)
    //   qk     : 16384x1024  bf16 (32 MB)
    //   partial: 16x32x4096  f32  ( 8 MB)
    //   attnT  : 32x4096     f32  (.5 MB)
    //   weffT  : 2x1024x1024 bf16 ( 4 MB)
    //   wfoldT : 2x1024x1024 bf16 ( 4 MB)
    unsigned short* xb     = (unsigned short*)d_ws;
    unsigned short* wqkT   = xb + (size_t)16384 * 1024;
    unsigned short* wvb    = wqkT + (size_t)1024 * 1024;
    unsigned short* qk     = wvb + (size_t)1024 * 1024;
    float*          partial= (float*)(qk + (size_t)16384 * 1024);
    float*          attnT  = partial + (size_t)16 * 32 * 4096;
    unsigned short* weffT  = (unsigned short*)(attnT + (size_t)32 * 4096);
    unsigned short* wfoldT = weffT + (size_t)2 * 1024 * 1024;

    cvt_all_kernel<<<18432, 256, 0, stream>>>(x, Wv, Wqk, xb, wvb, wqkT);

    // qk = x @ W_qk  (M=16384, N=1024, K=1024): 64 m-blks x 4 n-blks = 256
    gemm256_bt<1><<<256, 512, 0, stream>>>(
        xb, wqkT, (void*)qk, 1024, 1024, 1024, 1024, 0, 0, 0, 4, 8);

    gram_kernel<<<dim3(32, 16), 256, 0, stream>>>(qk, partial);
    softmax_kernel<<<512, 256, 0, stream>>>(partial, tau, attnT);
    wefft_kernel<<<dim3(32, 16), 256, 0, stream>>>(attnT, Wout, weffT);

    // WfoldT_b[j][c'] = sum_i WeffT_b[j][i] * W_v[c'][i]: small, keep 128^2
    gemm_bt<1><<<128, 256, 0, stream>>>(
        weffT, wvb, (void*)wfoldT, 1024, 1024, 1024, 1024,
        (size_t)1024 * 1024, 0, (size_t)1024 * 1024, 8, 1);

    // out_b = x_b @ Wfold_b  (M=8192/z, N=1024, K=1024): 32 m x 4 n x 2 z = 256
    gemm256_bt<0><<<256, 512, 0, stream>>>(
        xb, wfoldT, d_out, 1024, 1024, 1024, 1024,
        (size_t)8192 * 1024, (size_t)1024 * 1024, (size_t)8192 * 1024, 4, 4);
}

// Round 3
// 252.974 us; speedup vs baseline: 1.0452x; 1.0452x over previous
//
#include <hip/hip_runtime.h>
#include <hip/hip_bf16.h>
#include <cstdint>
#include <cstddef>

// MFMA fragment types (gfx950: V8y operands, V4f accumulator)
typedef __bf16 v8bf __attribute__((ext_vector_type(8)));
typedef float  v4f  __attribute__((ext_vector_type(4)));

__device__ __forceinline__ unsigned short f2bf(float f) {
    unsigned int u = __float_as_uint(f);
    u += 0x7fffu + ((u >> 16) & 1u);   // round-to-nearest-even
    return (unsigned short)(u >> 16);
}

// async global->LDS, 16B per lane. LDS deposit is wave-uniform base + lane*16;
// the GLOBAL source address is per-lane.
__device__ __forceinline__ void gload_lds16(const unsigned short* g, unsigned short* l) {
    __builtin_amdgcn_global_load_lds(
        (const __attribute__((address_space(1))) unsigned int*)(uintptr_t)g,
        (__attribute__((address_space(3))) unsigned int*)(uintptr_t)l, 16, 0, 0);
}

// ---------------------------------------------------------------------------
// Legacy 128x128 GEMM (kept only for the small Wfold GEMM, 128 blocks).
// C[M,N] = A[M,K] * B[K,N], B transposed (BT is N x K). bf16 in, fp32 acc.
// ---------------------------------------------------------------------------
template<int WRITE_BF16>
__global__ __launch_bounds__(256, 2) void gemm_bt(
    const unsigned short* __restrict__ A,   // M x K, row stride lda (bf16)
    const unsigned short* __restrict__ BT,  // N x K, row stride ldb (bf16)
    void* __restrict__ C,                   // M x N, row stride ldc
    int K, int lda, int ldb, int ldc,
    size_t sAz, size_t sBz, size_t sCz,     // per-z strides (elements)
    int nBlk, int mPerXcd)
{
    __shared__ unsigned short sA[128 * 32];
    __shared__ unsigned short sB[128 * 32];

    const int id = blockIdx.x;
    const int xcd = id & 7;
    int s = id >> 3;
    const int perXcd = mPerXcd * nBlk;
    const int z = s / perXcd;
    s -= z * perXcd;
    const int mB = xcd * mPerXcd + s / nBlk;
    const int nB = s - (s / nBlk) * nBlk;

    const unsigned short* Ab = A + (size_t)z * sAz;
    const unsigned short* Bb = BT + (size_t)z * sBz;

    const int tid  = threadIdx.x;
    const int wv   = tid >> 6;
    const int lane = tid & 63;
    const int quad = lane >> 4;
    const int l16  = lane & 15;
    const size_t bm = (size_t)mB * 128;
    const size_t bn = (size_t)nB * 128;
    const int wm = (wv >> 1) * 64;
    const int wn = (wv & 1) * 64;

    const int ro = tid >> 2;
    const int ko = (((tid & 3) ^ (ro & 3)) << 3);

    const unsigned short* aptr0 = Ab + (bm + ro)      * (size_t)lda + ko;
    const unsigned short* aptr1 = Ab + (bm + ro + 64) * (size_t)lda + ko;
    const unsigned short* bptr0 = Bb + (bn + ro)      * (size_t)ldb + ko;
    const unsigned short* bptr1 = Bb + (bn + ro + 64) * (size_t)ldb + ko;

    unsigned short* sA0 = &sA[wv * 512];
    unsigned short* sA1 = &sA[2048 + wv * 512];
    unsigned short* sB0 = &sB[wv * 512];
    unsigned short* sB1 = &sB[2048 + wv * 512];

    const int sslot = ((quad ^ (l16 & 3)) << 3);

    v4f acc[4][4] = {};

    for (int k0 = 0; k0 < K; k0 += 32) {
        gload_lds16(aptr0 + k0, sA0);
        gload_lds16(aptr1 + k0, sA1);
        gload_lds16(bptr0 + k0, sB0);
        gload_lds16(bptr1 + k0, sB1);
        __syncthreads();

        v8bf af[4], bfr[4];
        #pragma unroll
        for (int t = 0; t < 4; t++) {
            af[t]  = *(const v8bf*)&sA[(size_t)(wm + t * 16 + l16) * 32 + sslot];
            bfr[t] = *(const v8bf*)&sB[(size_t)(wn + t * 16 + l16) * 32 + sslot];
        }

        #pragma unroll
        for (int ti = 0; ti < 4; ti++)
            #pragma unroll
            for (int tj = 0; tj < 4; tj++)
                acc[ti][tj] = __builtin_amdgcn_mfma_f32_16x16x32_bf16(
                    af[ti], bfr[tj], acc[ti][tj], 0, 0, 0);
        __syncthreads();
    }

    if (WRITE_BF16) {
        unsigned short* Cb = (unsigned short*)C + (size_t)z * sCz;
        #pragma unroll
        for (int ti = 0; ti < 4; ti++) {
            const size_t row0 = bm + wm + ti * 16 + quad * 4;
            #pragma unroll
            for (int tj = 0; tj < 4; tj++) {
                const size_t col = bn + wn + tj * 16 + l16;
                #pragma unroll
                for (int r = 0; r < 4; r++)
                    Cb[(row0 + r) * (size_t)ldc + col] = f2bf(acc[ti][tj][r]);
            }
        }
    } else {
        float* Cb = (float*)C + (size_t)z * sCz;
        #pragma unroll
        for (int ti = 0; ti < 4; ti++) {
            const size_t row0 = bm + wm + ti * 16 + quad * 4;
            #pragma unroll
            for (int tj = 0; tj < 4; tj++) {
                const size_t col = bn + wn + tj * 16 + l16;
                #pragma unroll
                for (int r = 0; r < 4; r++)
                    Cb[(row0 + r) * (size_t)ldc + col] = acc[ti][tj][r];
            }
        }
    }
}

// ---------------------------------------------------------------------------
// 256x256-tile, BK=64, 8-wave (2Mx4N), 8-phase GEMM with counted vmcnt.
// ROUND-1 schedule (measured best: 44.2 us); round-2's sched_barrier pins and
// ph4 early-read regressed (49.0 us, m141-consistent) and are reverted.
// swapBig: when set, the XCD-contiguous "big" index is the N-block dim
// (for M=1024 x N=16384 shapes where M-blocks < 8).
// Phase map per K-tile t (p = t&1):
//   ph1: rd A(mh0)x8 + B(nh0)x4 ; stage A1(t+1) ; bar;lgkm0; MFMA(0,0); bar
//   ph2: rd B(nh1)x4            ; stage A0(t+2) ; bar;lgkm0; MFMA(0,1); bar
//   ph3: rd A(mh1)x8            ; stage B0(t+2) ; bar;lgkm0; MFMA(1,1); bar
//   ph4: stage B1(t+2); vmcnt(6)                ; bar;       MFMA(1,0); bar
// vmcnt(6) keeps exactly {A0,B0,B1}(t+2) in flight -> tile t+1 fully landed
// before its ph1 reads.  NT must be >= 2.
// ---------------------------------------------------------------------------
#define MFMA_QUAD(MH, NH)                                                     \
    do {                                                                      \
        __builtin_amdgcn_s_setprio(1);                                        \
        _Pragma("unroll")                                                     \
        for (int mi = 0; mi < 4; ++mi) {                                      \
            _Pragma("unroll")                                                 \
            for (int ni = 0; ni < 2; ++ni) {                                  \
                acc[(MH)*4 + mi][(NH)*2 + ni] =                               \
                    __builtin_amdgcn_mfma_f32_16x16x32_bf16(                  \
                        aF[mi][0], bF[NH][ni][0],                             \
                        acc[(MH)*4 + mi][(NH)*2 + ni], 0, 0, 0);              \
                acc[(MH)*4 + mi][(NH)*2 + ni] =                               \
                    __builtin_amdgcn_mfma_f32_16x16x32_bf16(                  \
                        aF[mi][1], bF[NH][ni][1],                             \
                        acc[(MH)*4 + mi][(NH)*2 + ni], 0, 0, 0);              \
            }                                                                 \
        }                                                                     \
        __builtin_amdgcn_s_setprio(0);                                        \
    } while (0)

template<int WRITE_BF16>
__global__ __launch_bounds__(512, 2) void gemm256_bt(
    const unsigned short* __restrict__ A,   // M x K (bf16), row stride lda
    const unsigned short* __restrict__ BT,  // N x K (bf16), row stride ldb
    void* __restrict__ C,                   // M x N, row stride ldc
    int K, int lda, int ldb, int ldc,
    size_t sAz, size_t sBz, size_t sCz,
    int nBlk, int mPerXcd, int swapBig)
{
    __shared__ unsigned short sm[65536];    // 128 KiB: [A|B][buf][half][128][64]

    const int id = blockIdx.x;
    const int xcd = id & 7;
    int s = id >> 3;
    const int perXcd = mPerXcd * nBlk;
    const int z = s / perXcd;
    s -= z * perXcd;
    const int bigB   = xcd * mPerXcd + s / nBlk;
    const int smallB = s - (s / nBlk) * nBlk;
    const int mB = swapBig ? smallB : bigB;
    const int nB = swapBig ? bigB : smallB;

    const unsigned short* Ab = A + (size_t)z * sAz;
    const unsigned short* Bb = BT + (size_t)z * sBz;

    const int tid  = threadIdx.x;
    const int wv   = tid >> 6;
    const int lane = tid & 63;
    const int quad = lane >> 4;
    const int l16  = lane & 15;
    const int wm   = wv >> 2;               // 0..1
    const int wn   = wv & 3;                // 0..3

    const size_t bm = (size_t)mB * 256;
    const size_t bn = (size_t)nB * 256;

    // staging source (per thread): within-half row r0 = tid>>3, logical 16B
    // slot slog = phys_slot ^ (row&7)  (phys slot = tid&7, row&7 == r0&7)
    const int r0   = tid >> 3;
    const int slog = (tid & 7) ^ (r0 & 7);
    const unsigned short* aP = Ab + (bm + r0) * (size_t)lda + slog * 8;
    const unsigned short* bP = Bb + (bn + r0) * (size_t)ldb + slog * 8;

    // stage dest (shorts, within half): wave-uniform base wv*512; j=1: +4096
    const int stA = wv * 512;

    // ds_read offsets (shorts): phys slot = (ks*4+quad) ^ (l16&7);
    // ks=1 slot = ks=0 slot ^ 4  ->  "^ 32" on the short offset.
    const int soff0 = (quad ^ (l16 & 7)) * 8;
    const int arow0 = (wm * 64 + l16) * 64 + soff0;
    const int brow0 = (wn * 32 + l16) * 64 + soff0;

    v4f  acc[8][4] = {};
    v8bf aF[4][2];          // A frags of current quadrant's M-half
    v8bf bF[2][2][2];       // [nh][ni][ks], nh0 lives ph1->ph4

    const int NT = K >> 6;

    // ---- prologue: stage tile0 (A0,A1,B0,B1) + tile1 (A0,B0,B1) ----
    {
        gload_lds16(aP,                sm + stA);
        gload_lds16(aP + 64 * lda,     sm + stA + 4096);
        gload_lds16(bP,                sm + 32768 + stA);
        gload_lds16(bP + 64 * ldb,     sm + 32768 + stA + 4096);
        gload_lds16(bP + 128 * ldb,    sm + 32768 + 8192 + stA);
        gload_lds16(bP + 192 * ldb,    sm + 32768 + 8192 + stA + 4096);
        gload_lds16(aP + 128 * lda,    sm + 8192 + stA);
        gload_lds16(aP + 192 * lda,    sm + 8192 + stA + 4096);
        if (NT > 1) {
            gload_lds16(aP + 64,                 sm + 16384 + stA);
            gload_lds16(aP + 64 * lda + 64,      sm + 16384 + stA + 4096);
            gload_lds16(bP + 64,                 sm + 32768 + 16384 + stA);
            gload_lds16(bP + 64 * ldb + 64,      sm + 32768 + 16384 + stA + 4096);
            gload_lds16(bP + 128 * ldb + 64,     sm + 32768 + 16384 + 8192 + stA);
            gload_lds16(bP + 192 * ldb + 64,     sm + 32768 + 16384 + 8192 + stA + 4096);
            asm volatile("s_waitcnt vmcnt(6)" ::: "memory");   // tile0 landed
        } else {
            asm volatile("s_waitcnt vmcnt(0)" ::: "memory");
        }
        __builtin_amdgcn_s_barrier();
    }

    for (int t = 0; t < NT; ++t) {
        const int p = t & 1;
        const unsigned short* sa = sm + p * 16384;
        const unsigned short* sb = sm + 32768 + p * 16384;
        unsigned short* dq = sm + (p ^ 1) * 16384;    // buf of tile t+1
        unsigned short* dp = sm + p * 16384;          // buf of tile t+2
        const int kk1 = (t + 1) * 64;
        const int kk2 = (t + 2) * 64;

        // ---- phase 1: read A(mh0) + B(nh0); stage A1(t+1) ----
        #pragma unroll
        for (int mi = 0; mi < 4; ++mi) {
            aF[mi][0] = *(const v8bf*)(sa + (arow0 + mi * 1024));
            aF[mi][1] = *(const v8bf*)(sa + ((arow0 + mi * 1024) ^ 32));
        }
        #pragma unroll
        for (int ni = 0; ni < 2; ++ni) {
            bF[0][ni][0] = *(const v8bf*)(sb + (brow0 + ni * 1024));
            bF[0][ni][1] = *(const v8bf*)(sb + ((brow0 + ni * 1024) ^ 32));
        }
        if (t + 1 < NT) {
            gload_lds16(aP + 128 * lda + kk1, dq + 8192 + stA);
            gload_lds16(aP + 192 * lda + kk1, dq + 8192 + stA + 4096);
        }
        __builtin_amdgcn_s_barrier();
        asm volatile("s_waitcnt lgkmcnt(0)" ::: "memory");
        MFMA_QUAD(0, 0);
        __builtin_amdgcn_s_barrier();

        // ---- phase 2: read B(nh1); stage A0(t+2) ----
        #pragma unroll
        for (int ni = 0; ni < 2; ++ni) {
            bF[1][ni][0] = *(const v8bf*)(sb + 8192 + (brow0 + ni * 1024));
            bF[1][ni][1] = *(const v8bf*)(sb + 8192 + ((brow0 + ni * 1024) ^ 32));
        }
        if (t + 2 < NT) {
            gload_lds16(aP + kk2,            dp + stA);
            gload_lds16(aP + 64 * lda + kk2, dp + stA + 4096);
        }
        __builtin_amdgcn_s_barrier();
        asm volatile("s_waitcnt lgkmcnt(0)" ::: "memory");
        MFMA_QUAD(0, 1);
        __builtin_amdgcn_s_barrier();

        // ---- phase 3: read A(mh1); stage B0(t+2) ----
        #pragma unroll
        for (int mi = 0; mi < 4; ++mi) {
            aF[mi][0] = *(const v8bf*)(sa + 8192 + (arow0 + mi * 1024));
            aF[mi][1] = *(const v8bf*)(sa + 8192 + ((arow0 + mi * 1024) ^ 32));
        }
        if (t + 2 < NT) {
            gload_lds16(bP + kk2,            dp + 32768 + stA);
            gload_lds16(bP + 64 * ldb + kk2, dp + 32768 + stA + 4096);
        }
        __builtin_amdgcn_s_barrier();
        asm volatile("s_waitcnt lgkmcnt(0)" ::: "memory");
        MFMA_QUAD(1, 1);
        __builtin_amdgcn_s_barrier();

        // ---- phase 4: stage B1(t+2); counted vmcnt (never 0 mid-loop) ----
        if (t + 2 < NT) {
            gload_lds16(bP + 128 * ldb + kk2, dp + 32768 + 8192 + stA);
            gload_lds16(bP + 192 * ldb + kk2, dp + 32768 + 8192 + stA + 4096);
            asm volatile("s_waitcnt vmcnt(6)" ::: "memory");
        } else {
            asm volatile("s_waitcnt vmcnt(0)" ::: "memory");
        }
        __builtin_amdgcn_s_barrier();
        MFMA_QUAD(1, 0);
        __builtin_amdgcn_s_barrier();
    }

    // ---- epilogue ----
    if (WRITE_BF16) {
        unsigned short* Cb = (unsigned short*)C + (size_t)z * sCz;
        #pragma unroll
        for (int mh = 0; mh < 2; ++mh)
            #pragma unroll
            for (int mi = 0; mi < 4; ++mi) {
                const size_t row0 = bm + mh * 128 + wm * 64 + mi * 16 + quad * 4;
                #pragma unroll
                for (int nh = 0; nh < 2; ++nh)
                    #pragma unroll
                    for (int ni = 0; ni < 2; ++ni) {
                        const size_t col = bn + nh * 128 + wn * 32 + ni * 16 + l16;
                        #pragma unroll
                        for (int r = 0; r < 4; ++r)
                            Cb[(row0 + r) * (size_t)ldc + col] =
                                f2bf(acc[mh * 4 + mi][nh * 2 + ni][r]);
                    }
            }
    } else {
        float* Cb = (float*)C + (size_t)z * sCz;
        #pragma unroll
        for (int mh = 0; mh < 2; ++mh)
            #pragma unroll
            for (int mi = 0; mi < 4; ++mi) {
                const size_t row0 = bm + mh * 128 + wm * 64 + mi * 16 + quad * 4;
                #pragma unroll
                for (int nh = 0; nh < 2; ++nh)
                    #pragma unroll
                    for (int ni = 0; ni < 2; ++ni) {
                        const size_t col = bn + nh * 128 + wn * 32 + ni * 16 + l16;
                        #pragma unroll
                        for (int r = 0; r < 4; ++r)
                            Cb[(row0 + r) * (size_t)ldc + col] =
                                acc[mh * 4 + mi][nh * 2 + ni][r];
                    }
            }
    }
}
#undef MFMA_QUAD

// ---------------------------------------------------------------------------
// Gram via MFMA from CHANNEL-MAJOR qkT: no LDS transpose at all.
// partial[split][bh][c][d] = sum_{n in split} qkT[c][n]*qkT[d][n].
// Per block: stage [64 ch][512 tok] = 64 KiB via global_load_lds (linear dest,
// inverse-swizzled source), then 16 K-steps of 32 with swizzled ds_read_b128.
// Swizzle: 16B slot p holds logical slot (p&56)|((p&7)^(row&7)) -> per-16-lane
// group the 8 slot classes are all hit (2 lanes/bank = free).
// 512 blocks = exactly 2 blocks/CU (128 KiB LDS).
// ---------------------------------------------------------------------------
__global__ __launch_bounds__(256, 2) void gram_kernel(
    const unsigned short* __restrict__ qkT,  // [1024 ch][16384 tok] bf16
    float* __restrict__ partial)             // [16][32][64][64]
{
    const int bh = blockIdx.x;               // b*16+h
    const int split = blockIdx.y;            // 0..15
    const int b = bh >> 4, h = bh & 15;
    const unsigned short* base =
        qkT + (size_t)(h * 64) * 16384 + (size_t)b * 8192 + (size_t)split * 512;

    __shared__ unsigned short sM[64 * 512];  // [ch][tok'], 64 KiB, slot-swizzled
    const int tid = threadIdx.x;
    const int wv = tid >> 6, lane = tid & 63, quad = lane >> 4, l16 = lane & 15;

    // stage: issue i covers rows i*4 + wv; lane deposits at phys slot = lane.
    #pragma unroll
    for (int i = 0; i < 16; i++) {
        const int row = i * 4 + wv;
        const int lo  = (lane & 56) | ((lane & 7) ^ (row & 7));
        gload_lds16(base + (size_t)row * 16384 + lo * 8,
                    sM + (size_t)i * 2048 + wv * 512);
    }
    __syncthreads();   // compiler drains vmcnt before the barrier

    v4f acc[4] = {};
    const int cha = 16 * wv + l16;

    #pragma unroll
    for (int ks = 0; ks < 16; ks++) {
        const int lg = ks * 4 + quad;                       // logical 16B chunk
        const int so = ((lg & 56) | ((lg & 7) ^ (l16 & 7))) * 8;  // shorts
        const v8bf a = *(const v8bf*)&sM[(size_t)cha * 512 + so];
        #pragma unroll
        for (int t = 0; t < 4; t++) {
            const v8bf bb = *(const v8bf*)&sM[(size_t)(t * 16 + l16) * 512 + so];
            acc[t] = __builtin_amdgcn_mfma_f32_16x16x32_bf16(a, bb, acc[t], 0, 0, 0);
        }
    }

    float* outp = partial + ((size_t)split * 32 + bh) * 4096;
    #pragma unroll
    for (int t = 0; t < 4; t++)
        #pragma unroll
        for (int r = 0; r < 4; r++)
            outp[(size_t)(16 * wv + quad * 4 + r) * 64 + t * 16 + l16] = acc[t][r];
}

// ---------------------------------------------------------------------------
// Softmax: one wave per (bh, c) row over d (64 lanes). Writes TRANSPOSED
// attnT[bh][d][c] so wefft can load without an LDS transpose.
// ---------------------------------------------------------------------------
__global__ __launch_bounds__(256) void softmax_kernel(
    const float* __restrict__ partial,   // [16][32][4096]
    const float* __restrict__ tau,       // [16]
    float* __restrict__ attnT)           // [32][64(d)][64(c)]
{
    const int gw = (int)((blockIdx.x * 256 + threadIdx.x) >> 6);  // 0..2047
    const int d = threadIdx.x & 63;
    const int bh = gw >> 6;
    const int c = gw & 63;
    const int h = bh & 15;

    float cd = 0.f, cc = 0.f, dd = 0.f;
    #pragma unroll
    for (int s = 0; s < 16; s++) {
        const float* p = partial + ((size_t)s * 32 + bh) * 4096;
        cd += p[c * 64 + d];
        cc += p[c * 65];
        dd += p[d * 65];
    }
    const float INV_SQRT_N = 0.011048543456039806f;  // 1/sqrt(8192)
    const float logit = (2.f * cd - cc - dd) * INV_SQRT_N * tau[h];

    float m = logit;
    #pragma unroll
    for (int off = 32; off > 0; off >>= 1) m = fmaxf(m, __shfl_xor(m, off, 64));
    const float e = __expf(logit - m);
    float sum = e;
    #pragma unroll
    for (int off = 32; off > 0; off >>= 1) sum += __shfl_xor(sum, off, 64);

    attnT[(size_t)bh * 4096 + d * 64 + c] = e / sum;
}

// ---------------------------------------------------------------------------
// WeffT[b][j][h*64+d] = sum_c attn[b,h,c,d] * W_out[h*64+c, j]   (bf16 out)
// ---------------------------------------------------------------------------
__global__ __launch_bounds__(256) void wefft_kernel(
    const float* __restrict__ attnT,      // [32][64(d)][64(c)]
    const float* __restrict__ Wout,       // [1024][1024] fp32
    unsigned short* __restrict__ weffT)   // [2][1024][1024] bf16 (j, i)
{
    const int bh = blockIdx.x;            // 0..31
    const int jg = blockIdx.y;            // 0..15
    const int b = bh >> 4, h = bh & 15;

    __shared__ float sAttT[64][65];       // [d][c]
    __shared__ float sW[64][65];          // [c][j_local]
    const int tid = threadIdx.x;
    const float* ap = attnT + (size_t)bh * 4096;
    const float* wp = Wout + (size_t)(h * 64) * 1024 + jg * 64;
    for (int i = tid; i < 4096; i += 256) {
        const int r = i >> 6, q = i & 63;
        sAttT[r][q] = ap[i];              // already transposed in global
        sW[r][q] = wp[(size_t)r * 1024 + q];
    }
    __syncthreads();

    const int dd0 = (tid >> 4) << 2;
    const int j0  = (tid & 15) << 2;
    float acc[4][4] = {};
    for (int cc = 0; cc < 64; cc++) {
        float av[4], wvv[4];
        #pragma unroll
        for (int i = 0; i < 4; i++) av[i] = sAttT[dd0 + i][cc];
        #pragma unroll
        for (int i = 0; i < 4; i++) wvv[i] = sW[cc][j0 + i];
        #pragma unroll
        for (int i = 0; i < 4; i++)
            #pragma unroll
            for (int j = 0; j < 4; j++)
                acc[i][j] += av[i] * wvv[j];
    }

    unsigned short* op = weffT + ((size_t)b * 1024 + jg * 64) * 1024 + h * 64;
    #pragma unroll
    for (int i = 0; i < 4; i++)
        #pragma unroll
        for (int j = 0; j < 4; j++)
            op[(size_t)(j0 + j) * 1024 + dd0 + i] = f2bf(acc[i][j]);
}

// ---------------------------------------------------------------------------
// Fused conversions: x -> bf16 (16384 blks), Wv -> bf16 (1024 blks),
// Wqk -> transposed bf16 (1024 tile blks). One dispatch.
// ---------------------------------------------------------------------------
__global__ __launch_bounds__(256) void cvt_all_kernel(
    const float* __restrict__ x, const float* __restrict__ Wv,
    const float* __restrict__ Wqk,
    unsigned short* __restrict__ xb, unsigned short* __restrict__ wvb,
    unsigned short* __restrict__ wqkT)
{
    const int bid = blockIdx.x;
    if (bid < 17408) {
        const float* src = (bid < 16384) ? x : Wv;
        unsigned short* dst = (bid < 16384) ? xb : wvb;
        const size_t blk = (bid < 16384) ? bid : (bid - 16384);
        const size_t i = (blk * 256 + threadIdx.x) * 4;
        const float4 v = *(const float4*)(src + i);
        ushort4 o;
        o.x = f2bf(v.x); o.y = f2bf(v.y); o.z = f2bf(v.z); o.w = f2bf(v.w);
        *(ushort4*)(dst + i) = o;
    } else {
        const int t = bid - 17408;
        const int n0 = (t & 31) * 32, k0 = (t >> 5) * 32;
        __shared__ float sT[32][33];
        const int tx = threadIdx.x & 31, ty = threadIdx.x >> 5;
        #pragma unroll
        for (int i = ty; i < 32; i += 8)
            sT[i][tx] = Wqk[(size_t)(k0 + i) * 1024 + n0 + tx];
        __syncthreads();
        #pragma unroll
        for (int i = ty; i < 32; i += 8)
            wqkT[(size_t)(n0 + i) * 1024 + k0 + tx] = f2bf(sT[tx][i]);
    }
}

// ---------------------------------------------------------------------------
extern "C" void kernel_launch(void* const* d_in, const int* in_sizes, int n_in,
                              void* d_out, int out_size, void* d_ws, size_t ws_size,
                              hipStream_t stream)
{
    (void)in_sizes; (void)n_in; (void)out_size; (void)ws_size;
    const float* x    = (const float*)d_in[0];
    const float* Wqk  = (const float*)d_in[1];
    const float* Wv   = (const float*)d_in[2];
    const float* Wout = (const float*)d_in[3];
    const float* tau  = (const float*)d_in[4];

    // out_b = x_b @ (W_v @ Weff_b); v never materialized.
    // qk is computed TRANSPOSED (qkT = Wqk^T @ x^T, channel-major) so gram
    // needs no LDS transpose.
    // ws layout:
    //   xb     : 16384x1024  bf16 (32 MB)
    //   wqkT   : 1024x1024   bf16 ( 2 MB)
    //   wvb    : 1024x1024   bf16 ( 2 MB)
    //   qkT    : 1024x16384  bf16 (32 MB)
    //   partial: 16x32x4096  f32  ( 8 MB)
    //   attnT  : 32x4096     f32  (.5 MB)
    //   weffT  : 2x1024x1024 bf16 ( 4 MB)
    //   wfoldT : 2x1024x1024 bf16 ( 4 MB)
    unsigned short* xb     = (unsigned short*)d_ws;
    unsigned short* wqkT   = xb + (size_t)16384 * 1024;
    unsigned short* wvb    = wqkT + (size_t)1024 * 1024;
    unsigned short* qkT    = wvb + (size_t)1024 * 1024;
    float*          partial= (float*)(qkT + (size_t)16384 * 1024);
    float*          attnT  = partial + (size_t)16 * 32 * 4096;
    unsigned short* weffT  = (unsigned short*)(attnT + (size_t)32 * 4096);
    unsigned short* wfoldT = weffT + (size_t)2 * 1024 * 1024;

    cvt_all_kernel<<<18432, 256, 0, stream>>>(x, Wv, Wqk, xb, wvb, wqkT);

    // qkT = Wqk^T @ x^T: C[c][n], M=1024 (4 m-blks), N=16384 (64 n-blks).
    // swapBig=1: each XCD owns 8 contiguous n-blocks (token range); the 4
    // m-blocks per n-strip are adjacent in dispatch order (share B strip).
    gemm256_bt<1><<<256, 512, 0, stream>>>(
        wqkT, xb, (void*)qkT, 1024, 1024, 1024, 16384, 0, 0, 0, 4, 8, 1);

    gram_kernel<<<dim3(32, 16), 256, 0, stream>>>(qkT, partial);
    softmax_kernel<<<512, 256, 0, stream>>>(partial, tau, attnT);
    wefft_kernel<<<dim3(32, 16), 256, 0, stream>>>(attnT, Wout, weffT);

    // WfoldT_b[j][c'] = sum_i WeffT_b[j][i] * W_v[c'][i]: small, keep 128^2
    gemm_bt<1><<<128, 256, 0, stream>>>(
        weffT, wvb, (void*)wfoldT, 1024, 1024, 1024, 1024,
        (size_t)1024 * 1024, 0, (size_t)1024 * 1024, 8, 1);

    // out_b = x_b @ Wfold_b  (M=8192/z, N=1024, K=1024): 32 m x 4 n x 2 z = 256
    gemm256_bt<0><<<256, 512, 0, stream>>>(
        xb, wfoldT, d_out, 1024, 1024, 1024, 1024,
        (size_t)8192 * 1024, (size_t)1024 * 1024, (size_t)8192 * 1024, 4, 4, 0);
}

// Round 4
// 252.282 us; speedup vs baseline: 1.0481x; 1.0027x over previous
//
#include <hip/hip_runtime.h>
#include <hip/hip_bf16.h>
#include <cstdint>
#include <cstddef>

// MFMA fragment types (gfx950: V8y operands, V4f accumulator)
typedef __bf16 v8bf __attribute__((ext_vector_type(8)));
typedef float  v4f  __attribute__((ext_vector_type(4)));

__device__ __forceinline__ unsigned short f2bf(float f) {
    unsigned int u = __float_as_uint(f);
    u += 0x7fffu + ((u >> 16) & 1u);   // round-to-nearest-even
    return (unsigned short)(u >> 16);
}

// async global->LDS, 16B per lane. LDS deposit is wave-uniform base + lane*16;
// the GLOBAL source address is per-lane.
__device__ __forceinline__ void gload_lds16(const unsigned short* g, unsigned short* l) {
    __builtin_amdgcn_global_load_lds(
        (const __attribute__((address_space(1))) unsigned int*)(uintptr_t)g,
        (__attribute__((address_space(3))) unsigned int*)(uintptr_t)l, 16, 0, 0);
}

// ---------------------------------------------------------------------------
// Legacy 128x128 GEMM (kept only for the small Wfold GEMM, 128 blocks).
// C[M,N] = A[M,K] * B[K,N], B transposed (BT is N x K). bf16 in, fp32 acc.
// ---------------------------------------------------------------------------
template<int WRITE_BF16>
__global__ __launch_bounds__(256, 2) void gemm_bt(
    const unsigned short* __restrict__ A,   // M x K, row stride lda (bf16)
    const unsigned short* __restrict__ BT,  // N x K, row stride ldb (bf16)
    void* __restrict__ C,                   // M x N, row stride ldc
    int K, int lda, int ldb, int ldc,
    size_t sAz, size_t sBz, size_t sCz,     // per-z strides (elements)
    int nBlk, int mPerXcd)
{
    __shared__ unsigned short sA[128 * 32];
    __shared__ unsigned short sB[128 * 32];

    const int id = blockIdx.x;
    const int xcd = id & 7;
    int s = id >> 3;
    const int perXcd = mPerXcd * nBlk;
    const int z = s / perXcd;
    s -= z * perXcd;
    const int mB = xcd * mPerXcd + s / nBlk;
    const int nB = s - (s / nBlk) * nBlk;

    const unsigned short* Ab = A + (size_t)z * sAz;
    const unsigned short* Bb = BT + (size_t)z * sBz;

    const int tid  = threadIdx.x;
    const int wv   = tid >> 6;
    const int lane = tid & 63;
    const int quad = lane >> 4;
    const int l16  = lane & 15;
    const size_t bm = (size_t)mB * 128;
    const size_t bn = (size_t)nB * 128;
    const int wm = (wv >> 1) * 64;
    const int wn = (wv & 1) * 64;

    const int ro = tid >> 2;
    const int ko = (((tid & 3) ^ (ro & 3)) << 3);

    const unsigned short* aptr0 = Ab + (bm + ro)      * (size_t)lda + ko;
    const unsigned short* aptr1 = Ab + (bm + ro + 64) * (size_t)lda + ko;
    const unsigned short* bptr0 = Bb + (bn + ro)      * (size_t)ldb + ko;
    const unsigned short* bptr1 = Bb + (bn + ro + 64) * (size_t)ldb + ko;

    unsigned short* sA0 = &sA[wv * 512];
    unsigned short* sA1 = &sA[2048 + wv * 512];
    unsigned short* sB0 = &sB[wv * 512];
    unsigned short* sB1 = &sB[2048 + wv * 512];

    const int sslot = ((quad ^ (l16 & 3)) << 3);

    v4f acc[4][4] = {};

    for (int k0 = 0; k0 < K; k0 += 32) {
        gload_lds16(aptr0 + k0, sA0);
        gload_lds16(aptr1 + k0, sA1);
        gload_lds16(bptr0 + k0, sB0);
        gload_lds16(bptr1 + k0, sB1);
        __syncthreads();

        v8bf af[4], bfr[4];
        #pragma unroll
        for (int t = 0; t < 4; t++) {
            af[t]  = *(const v8bf*)&sA[(size_t)(wm + t * 16 + l16) * 32 + sslot];
            bfr[t] = *(const v8bf*)&sB[(size_t)(wn + t * 16 + l16) * 32 + sslot];
        }

        #pragma unroll
        for (int ti = 0; ti < 4; ti++)
            #pragma unroll
            for (int tj = 0; tj < 4; tj++)
                acc[ti][tj] = __builtin_amdgcn_mfma_f32_16x16x32_bf16(
                    af[ti], bfr[tj], acc[ti][tj], 0, 0, 0);
        __syncthreads();
    }

    if (WRITE_BF16) {
        unsigned short* Cb = (unsigned short*)C + (size_t)z * sCz;
        #pragma unroll
        for (int ti = 0; ti < 4; ti++) {
            const size_t row0 = bm + wm + ti * 16 + quad * 4;
            #pragma unroll
            for (int tj = 0; tj < 4; tj++) {
                const size_t col = bn + wn + tj * 16 + l16;
                #pragma unroll
                for (int r = 0; r < 4; r++)
                    Cb[(row0 + r) * (size_t)ldc + col] = f2bf(acc[ti][tj][r]);
            }
        }
    } else {
        float* Cb = (float*)C + (size_t)z * sCz;
        #pragma unroll
        for (int ti = 0; ti < 4; ti++) {
            const size_t row0 = bm + wm + ti * 16 + quad * 4;
            #pragma unroll
            for (int tj = 0; tj < 4; tj++) {
                const size_t col = bn + wn + tj * 16 + l16;
                #pragma unroll
                for (int r = 0; r < 4; r++)
                    Cb[(row0 + r) * (size_t)ldc + col] = acc[ti][tj][r];
            }
        }
    }
}

// ---------------------------------------------------------------------------
// 256x256-tile, BK=64, 8-wave (2Mx4N), 8-phase GEMM with counted vmcnt.
// ROUND-4 change: the asm "s_waitcnt lgkmcnt(0)" drains (with "memory"
// clobbers) are REMOVED.  Those pins serialized the LDS-read drain with the
// MFMA cluster (measured: 6750 cyc/K-tile vs 2480 MFMA + 2300 LDS if
// serialized).  The ds_reads are compiler-visible, so the compiler emits
// fine-grained lgkmcnt(N) before each consuming MFMA: the first MFMA starts
// after its own operands return and overlaps the remaining read drain.
// Safety: every ds_read's consumer MFMA precedes the phase's closing
// barrier, so all reads are drained before any later stage overwrites the
// region; vmcnt asms keep "memory" so no read hoists above a tile-landing
// guarantee.  ph1 reads are issued in consumption order (aF0, b00, b01,
// aF1..3) so in-order lgkm returns release the first MFMA after 4 reads.
// Phase map per K-tile t (p = t&1):
//   ph1: rd A(mh0)x8 + B(nh0)x4 ; stage A1(t+1) ; bar; MFMA(0,0); bar
//   ph2: rd B(nh1)x4            ; stage A0(t+2) ; bar; MFMA(0,1); bar
//   ph3: rd A(mh1)x8            ; stage B0(t+2) ; bar; MFMA(1,1); bar
//   ph4: stage B1(t+2); vmcnt(6)                ; bar; MFMA(1,0); bar
// vmcnt(6) keeps exactly {A0,B0,B1}(t+2) in flight -> tile t+1 fully landed
// before its ph1 reads.  NT must be >= 2.
// ---------------------------------------------------------------------------
#define MFMA_QUAD(MH, NH)                                                     \
    do {                                                                      \
        __builtin_amdgcn_s_setprio(1);                                        \
        _Pragma("unroll")                                                     \
        for (int mi = 0; mi < 4; ++mi) {                                      \
            _Pragma("unroll")                                                 \
            for (int ni = 0; ni < 2; ++ni) {                                  \
                acc[(MH)*4 + mi][(NH)*2 + ni] =                               \
                    __builtin_amdgcn_mfma_f32_16x16x32_bf16(                  \
                        aF[mi][0], bF[NH][ni][0],                             \
                        acc[(MH)*4 + mi][(NH)*2 + ni], 0, 0, 0);              \
                acc[(MH)*4 + mi][(NH)*2 + ni] =                               \
                    __builtin_amdgcn_mfma_f32_16x16x32_bf16(                  \
                        aF[mi][1], bF[NH][ni][1],                             \
                        acc[(MH)*4 + mi][(NH)*2 + ni], 0, 0, 0);              \
            }                                                                 \
        }                                                                     \
        __builtin_amdgcn_s_setprio(0);                                        \
    } while (0)

template<int WRITE_BF16>
__global__ __launch_bounds__(512, 2) void gemm256_bt(
    const unsigned short* __restrict__ A,   // M x K (bf16), row stride lda
    const unsigned short* __restrict__ BT,  // N x K (bf16), row stride ldb
    void* __restrict__ C,                   // M x N, row stride ldc
    int K, int lda, int ldb, int ldc,
    size_t sAz, size_t sBz, size_t sCz,
    int nBlk, int mPerXcd, int swapBig)
{
    __shared__ unsigned short sm[65536];    // 128 KiB: [A|B][buf][half][128][64]

    const int id = blockIdx.x;
    const int xcd = id & 7;
    int s = id >> 3;
    const int perXcd = mPerXcd * nBlk;
    const int z = s / perXcd;
    s -= z * perXcd;
    const int bigB   = xcd * mPerXcd + s / nBlk;
    const int smallB = s - (s / nBlk) * nBlk;
    const int mB = swapBig ? smallB : bigB;
    const int nB = swapBig ? bigB : smallB;

    const unsigned short* Ab = A + (size_t)z * sAz;
    const unsigned short* Bb = BT + (size_t)z * sBz;

    const int tid  = threadIdx.x;
    const int wv   = tid >> 6;
    const int lane = tid & 63;
    const int quad = lane >> 4;
    const int l16  = lane & 15;
    const int wm   = wv >> 2;               // 0..1
    const int wn   = wv & 3;                // 0..3

    const size_t bm = (size_t)mB * 256;
    const size_t bn = (size_t)nB * 256;

    // staging source (per thread): within-half row r0 = tid>>3, logical 16B
    // slot slog = phys_slot ^ (row&7)  (phys slot = tid&7, row&7 == r0&7)
    const int r0   = tid >> 3;
    const int slog = (tid & 7) ^ (r0 & 7);
    const unsigned short* aP = Ab + (bm + r0) * (size_t)lda + slog * 8;
    const unsigned short* bP = Bb + (bn + r0) * (size_t)ldb + slog * 8;

    // stage dest (shorts, within half): wave-uniform base wv*512; j=1: +4096
    const int stA = wv * 512;

    // ds_read offsets (shorts): phys slot = (ks*4+quad) ^ (l16&7);
    // ks=1 slot = ks=0 slot ^ 4  ->  "^ 32" on the short offset.
    const int soff0 = (quad ^ (l16 & 7)) * 8;
    const int arow0 = (wm * 64 + l16) * 64 + soff0;
    const int brow0 = (wn * 32 + l16) * 64 + soff0;

    v4f  acc[8][4] = {};
    v8bf aF[4][2];          // A frags of current quadrant's M-half
    v8bf bF[2][2][2];       // [nh][ni][ks], nh0 lives ph1->ph4

    const int NT = K >> 6;

    // ---- prologue: stage tile0 (A0,A1,B0,B1) + tile1 (A0,B0,B1) ----
    {
        gload_lds16(aP,                sm + stA);
        gload_lds16(aP + 64 * lda,     sm + stA + 4096);
        gload_lds16(bP,                sm + 32768 + stA);
        gload_lds16(bP + 64 * ldb,     sm + 32768 + stA + 4096);
        gload_lds16(bP + 128 * ldb,    sm + 32768 + 8192 + stA);
        gload_lds16(bP + 192 * ldb,    sm + 32768 + 8192 + stA + 4096);
        gload_lds16(aP + 128 * lda,    sm + 8192 + stA);
        gload_lds16(aP + 192 * lda,    sm + 8192 + stA + 4096);
        if (NT > 1) {
            gload_lds16(aP + 64,                 sm + 16384 + stA);
            gload_lds16(aP + 64 * lda + 64,      sm + 16384 + stA + 4096);
            gload_lds16(bP + 64,                 sm + 32768 + 16384 + stA);
            gload_lds16(bP + 64 * ldb + 64,      sm + 32768 + 16384 + stA + 4096);
            gload_lds16(bP + 128 * ldb + 64,     sm + 32768 + 16384 + 8192 + stA);
            gload_lds16(bP + 192 * ldb + 64,     sm + 32768 + 16384 + 8192 + stA + 4096);
            asm volatile("s_waitcnt vmcnt(6)" ::: "memory");   // tile0 landed
        } else {
            asm volatile("s_waitcnt vmcnt(0)" ::: "memory");
        }
        __builtin_amdgcn_s_barrier();
    }

    for (int t = 0; t < NT; ++t) {
        const int p = t & 1;
        const unsigned short* sa = sm + p * 16384;
        const unsigned short* sb = sm + 32768 + p * 16384;
        unsigned short* dq = sm + (p ^ 1) * 16384;    // buf of tile t+1
        unsigned short* dp = sm + p * 16384;          // buf of tile t+2
        const int kk1 = (t + 1) * 64;
        const int kk2 = (t + 2) * 64;

        // ---- phase 1: read A(mh0) + B(nh0) in consumption order;
        //      stage A1(t+1) ----
        aF[0][0] = *(const v8bf*)(sa + (arow0));
        aF[0][1] = *(const v8bf*)(sa + ((arow0) ^ 32));
        bF[0][0][0] = *(const v8bf*)(sb + (brow0));
        bF[0][0][1] = *(const v8bf*)(sb + ((brow0) ^ 32));
        bF[0][1][0] = *(const v8bf*)(sb + (brow0 + 1024));
        bF[0][1][1] = *(const v8bf*)(sb + ((brow0 + 1024) ^ 32));
        #pragma unroll
        for (int mi = 1; mi < 4; ++mi) {
            aF[mi][0] = *(const v8bf*)(sa + (arow0 + mi * 1024));
            aF[mi][1] = *(const v8bf*)(sa + ((arow0 + mi * 1024) ^ 32));
        }
        if (t + 1 < NT) {
            gload_lds16(aP + 128 * lda + kk1, dq + 8192 + stA);
            gload_lds16(aP + 192 * lda + kk1, dq + 8192 + stA + 4096);
        }
        __builtin_amdgcn_s_barrier();
        MFMA_QUAD(0, 0);
        __builtin_amdgcn_s_barrier();

        // ---- phase 2: read B(nh1); stage A0(t+2) ----
        #pragma unroll
        for (int ni = 0; ni < 2; ++ni) {
            bF[1][ni][0] = *(const v8bf*)(sb + 8192 + (brow0 + ni * 1024));
            bF[1][ni][1] = *(const v8bf*)(sb + 8192 + ((brow0 + ni * 1024) ^ 32));
        }
        if (t + 2 < NT) {
            gload_lds16(aP + kk2,            dp + stA);
            gload_lds16(aP + 64 * lda + kk2, dp + stA + 4096);
        }
        __builtin_amdgcn_s_barrier();
        MFMA_QUAD(0, 1);
        __builtin_amdgcn_s_barrier();

        // ---- phase 3: read A(mh1); stage B0(t+2) ----
        #pragma unroll
        for (int mi = 0; mi < 4; ++mi) {
            aF[mi][0] = *(const v8bf*)(sa + 8192 + (arow0 + mi * 1024));
            aF[mi][1] = *(const v8bf*)(sa + 8192 + ((arow0 + mi * 1024) ^ 32));
        }
        if (t + 2 < NT) {
            gload_lds16(bP + kk2,            dp + 32768 + stA);
            gload_lds16(bP + 64 * ldb + kk2, dp + 32768 + stA + 4096);
        }
        __builtin_amdgcn_s_barrier();
        MFMA_QUAD(1, 1);
        __builtin_amdgcn_s_barrier();

        // ---- phase 4: stage B1(t+2); counted vmcnt (never 0 mid-loop) ----
        if (t + 2 < NT) {
            gload_lds16(bP + 128 * ldb + kk2, dp + 32768 + 8192 + stA);
            gload_lds16(bP + 192 * ldb + kk2, dp + 32768 + 8192 + stA + 4096);
            asm volatile("s_waitcnt vmcnt(6)" ::: "memory");
        } else {
            asm volatile("s_waitcnt vmcnt(0)" ::: "memory");
        }
        __builtin_amdgcn_s_barrier();
        MFMA_QUAD(1, 0);
        __builtin_amdgcn_s_barrier();
    }

    // ---- epilogue ----
    if (WRITE_BF16) {
        unsigned short* Cb = (unsigned short*)C + (size_t)z * sCz;
        #pragma unroll
        for (int mh = 0; mh < 2; ++mh)
            #pragma unroll
            for (int mi = 0; mi < 4; ++mi) {
                const size_t row0 = bm + mh * 128 + wm * 64 + mi * 16 + quad * 4;
                #pragma unroll
                for (int nh = 0; nh < 2; ++nh)
                    #pragma unroll
                    for (int ni = 0; ni < 2; ++ni) {
                        const size_t col = bn + nh * 128 + wn * 32 + ni * 16 + l16;
                        #pragma unroll
                        for (int r = 0; r < 4; ++r)
                            Cb[(row0 + r) * (size_t)ldc + col] =
                                f2bf(acc[mh * 4 + mi][nh * 2 + ni][r]);
                    }
            }
    } else {
        float* Cb = (float*)C + (size_t)z * sCz;
        #pragma unroll
        for (int mh = 0; mh < 2; ++mh)
            #pragma unroll
            for (int mi = 0; mi < 4; ++mi) {
                const size_t row0 = bm + mh * 128 + wm * 64 + mi * 16 + quad * 4;
                #pragma unroll
                for (int nh = 0; nh < 2; ++nh)
                    #pragma unroll
                    for (int ni = 0; ni < 2; ++ni) {
                        const size_t col = bn + nh * 128 + wn * 32 + ni * 16 + l16;
                        #pragma unroll
                        for (int r = 0; r < 4; ++r)
                            Cb[(row0 + r) * (size_t)ldc + col] =
                                acc[mh * 4 + mi][nh * 2 + ni][r];
                    }
            }
    }
}
#undef MFMA_QUAD

// ---------------------------------------------------------------------------
// Gram via MFMA from CHANNEL-MAJOR qkT: no LDS transpose at all.
// partial[split][bh][c][d] = sum_{n in split} qkT[c][n]*qkT[d][n].
// Per block: stage [64 ch][512 tok] = 64 KiB via global_load_lds (linear dest,
// inverse-swizzled source), then 16 K-steps of 32 with swizzled ds_read_b128.
// Swizzle: 16B slot p holds logical slot (p&56)|((p&7)^(row&7)) -> per-16-lane
// group the 8 slot classes are all hit (2 lanes/bank = free).
// 512 blocks = exactly 2 blocks/CU (128 KiB LDS).
// ---------------------------------------------------------------------------
__global__ __launch_bounds__(256, 2) void gram_kernel(
    const unsigned short* __restrict__ qkT,  // [1024 ch][16384 tok] bf16
    float* __restrict__ partial)             // [16][32][64][64]
{
    const int bh = blockIdx.x;               // b*16+h
    const int split = blockIdx.y;            // 0..15
    const int b = bh >> 4, h = bh & 15;
    const unsigned short* base =
        qkT + (size_t)(h * 64) * 16384 + (size_t)b * 8192 + (size_t)split * 512;

    __shared__ unsigned short sM[64 * 512];  // [ch][tok'], 64 KiB, slot-swizzled
    const int tid = threadIdx.x;
    const int wv = tid >> 6, lane = tid & 63, quad = lane >> 4, l16 = lane & 15;

    // stage: issue i covers rows i*4 + wv; lane deposits at phys slot = lane.
    #pragma unroll
    for (int i = 0; i < 16; i++) {
        const int row = i * 4 + wv;
        const int lo  = (lane & 56) | ((lane & 7) ^ (row & 7));
        gload_lds16(base + (size_t)row * 16384 + lo * 8,
                    sM + (size_t)i * 2048 + wv * 512);
    }
    __syncthreads();   // compiler drains vmcnt before the barrier

    v4f acc[4] = {};
    const int cha = 16 * wv + l16;

    #pragma unroll
    for (int ks = 0; ks < 16; ks++) {
        const int lg = ks * 4 + quad;                       // logical 16B chunk
        const int so = ((lg & 56) | ((lg & 7) ^ (l16 & 7))) * 8;  // shorts
        const v8bf a = *(const v8bf*)&sM[(size_t)cha * 512 + so];
        #pragma unroll
        for (int t = 0; t < 4; t++) {
            const v8bf bb = *(const v8bf*)&sM[(size_t)(t * 16 + l16) * 512 + so];
            acc[t] = __builtin_amdgcn_mfma_f32_16x16x32_bf16(a, bb, acc[t], 0, 0, 0);
        }
    }

    float* outp = partial + ((size_t)split * 32 + bh) * 4096;
    #pragma unroll
    for (int t = 0; t < 4; t++)
        #pragma unroll
        for (int r = 0; r < 4; r++)
            outp[(size_t)(16 * wv + quad * 4 + r) * 64 + t * 16 + l16] = acc[t][r];
}

// ---------------------------------------------------------------------------
// Softmax: one wave per (bh, c) row over d (64 lanes). Writes TRANSPOSED
// attnT[bh][d][c] so wefft can load without an LDS transpose.
// ---------------------------------------------------------------------------
__global__ __launch_bounds__(256) void softmax_kernel(
    const float* __restrict__ partial,   // [16][32][4096]
    const float* __restrict__ tau,       // [16]
    float* __restrict__ attnT)           // [32][64(d)][64(c)]
{
    const int gw = (int)((blockIdx.x * 256 + threadIdx.x) >> 6);  // 0..2047
    const int d = threadIdx.x & 63;
    const int bh = gw >> 6;
    const int c = gw & 63;
    const int h = bh & 15;

    float cd = 0.f, cc = 0.f, dd = 0.f;
    #pragma unroll
    for (int s = 0; s < 16; s++) {
        const float* p = partial + ((size_t)s * 32 + bh) * 4096;
        cd += p[c * 64 + d];
        cc += p[c * 65];
        dd += p[d * 65];
    }
    const float INV_SQRT_N = 0.011048543456039806f;  // 1/sqrt(8192)
    const float logit = (2.f * cd - cc - dd) * INV_SQRT_N * tau[h];

    float m = logit;
    #pragma unroll
    for (int off = 32; off > 0; off >>= 1) m = fmaxf(m, __shfl_xor(m, off, 64));
    const float e = __expf(logit - m);
    float sum = e;
    #pragma unroll
    for (int off = 32; off > 0; off >>= 1) sum += __shfl_xor(sum, off, 64);

    attnT[(size_t)bh * 4096 + d * 64 + c] = e / sum;
}

// ---------------------------------------------------------------------------
// WeffT[b][j][h*64+d] = sum_c attn[b,h,c,d] * W_out[h*64+c, j]   (bf16 out)
// ---------------------------------------------------------------------------
__global__ __launch_bounds__(256) void wefft_kernel(
    const float* __restrict__ attnT,      // [32][64(d)][64(c)]
    const float* __restrict__ Wout,       // [1024][1024] fp32
    unsigned short* __restrict__ weffT)   // [2][1024][1024] bf16 (j, i)
{
    const int bh = blockIdx.x;            // 0..31
    const int jg = blockIdx.y;            // 0..15
    const int b = bh >> 4, h = bh & 15;

    __shared__ float sAttT[64][65];       // [d][c]
    __shared__ float sW[64][65];          // [c][j_local]
    const int tid = threadIdx.x;
    const float* ap = attnT + (size_t)bh * 4096;
    const float* wp = Wout + (size_t)(h * 64) * 1024 + jg * 64;
    for (int i = tid; i < 4096; i += 256) {
        const int r = i >> 6, q = i & 63;
        sAttT[r][q] = ap[i];              // already transposed in global
        sW[r][q] = wp[(size_t)r * 1024 + q];
    }
    __syncthreads();

    const int dd0 = (tid >> 4) << 2;
    const int j0  = (tid & 15) << 2;
    float acc[4][4] = {};
    for (int cc = 0; cc < 64; cc++) {
        float av[4], wvv[4];
        #pragma unroll
        for (int i = 0; i < 4; i++) av[i] = sAttT[dd0 + i][cc];
        #pragma unroll
        for (int i = 0; i < 4; i++) wvv[i] = sW[cc][j0 + i];
        #pragma unroll
        for (int i = 0; i < 4; i++)
            #pragma unroll
            for (int j = 0; j < 4; j++)
                acc[i][j] += av[i] * wvv[j];
    }

    unsigned short* op = weffT + ((size_t)b * 1024 + jg * 64) * 1024 + h * 64;
    #pragma unroll
    for (int i = 0; i < 4; i++)
        #pragma unroll
        for (int j = 0; j < 4; j++)
            op[(size_t)(j0 + j) * 1024 + dd0 + i] = f2bf(acc[i][j]);
}

// ---------------------------------------------------------------------------
// Fused conversions: x -> bf16 (16384 blks), Wv -> bf16 (1024 blks),
// Wqk -> transposed bf16 (1024 tile blks). One dispatch.
// ---------------------------------------------------------------------------
__global__ __launch_bounds__(256) void cvt_all_kernel(
    const float* __restrict__ x, const float* __restrict__ Wv,
    const float* __restrict__ Wqk,
    unsigned short* __restrict__ xb, unsigned short* __restrict__ wvb,
    unsigned short* __restrict__ wqkT)
{
    const int bid = blockIdx.x;
    if (bid < 17408) {
        const float* src = (bid < 16384) ? x : Wv;
        unsigned short* dst = (bid < 16384) ? xb : wvb;
        const size_t blk = (bid < 16384) ? bid : (bid - 16384);
        const size_t i = (blk * 256 + threadIdx.x) * 4;
        const float4 v = *(const float4*)(src + i);
        ushort4 o;
        o.x = f2bf(v.x); o.y = f2bf(v.y); o.z = f2bf(v.z); o.w = f2bf(v.w);
        *(ushort4*)(dst + i) = o;
    } else {
        const int t = bid - 17408;
        const int n0 = (t & 31) * 32, k0 = (t >> 5) * 32;
        __shared__ float sT[32][33];
        const int tx = threadIdx.x & 31, ty = threadIdx.x >> 5;
        #pragma unroll
        for (int i = ty; i < 32; i += 8)
            sT[i][tx] = Wqk[(size_t)(k0 + i) * 1024 + n0 + tx];
        __syncthreads();
        #pragma unroll
        for (int i = ty; i < 32; i += 8)
            wqkT[(size_t)(n0 + i) * 1024 + k0 + tx] = f2bf(sT[tx][i]);
    }
}

// ---------------------------------------------------------------------------
extern "C" void kernel_launch(void* const* d_in, const int* in_sizes, int n_in,
                              void* d_out, int out_size, void* d_ws, size_t ws_size,
                              hipStream_t stream)
{
    (void)in_sizes; (void)n_in; (void)out_size; (void)ws_size;
    const float* x    = (const float*)d_in[0];
    const float* Wqk  = (const float*)d_in[1];
    const float* Wv   = (const float*)d_in[2];
    const float* Wout = (const float*)d_in[3];
    const float* tau  = (const float*)d_in[4];

    // out_b = x_b @ (W_v @ Weff_b); v never materialized.
    // qk is computed TRANSPOSED (qkT = Wqk^T @ x^T, channel-major) so gram
    // needs no LDS transpose.
    // ws layout:
    //   xb     : 16384x1024  bf16 (32 MB)
    //   wqkT   : 1024x1024   bf16 ( 2 MB)
    //   wvb    : 1024x1024   bf16 ( 2 MB)
    //   qkT    : 1024x16384  bf16 (32 MB)
    //   partial: 16x32x4096  f32  ( 8 MB)
    //   attnT  : 32x4096     f32  (.5 MB)
    //   weffT  : 2x1024x1024 bf16 ( 4 MB)
    //   wfoldT : 2x1024x1024 bf16 ( 4 MB)
    unsigned short* xb     = (unsigned short*)d_ws;
    unsigned short* wqkT   = xb + (size_t)16384 * 1024;
    unsigned short* wvb    = wqkT + (size_t)1024 * 1024;
    unsigned short* qkT    = wvb + (size_t)1024 * 1024;
    float*          partial= (float*)(qkT + (size_t)16384 * 1024);
    float*          attnT  = partial + (size_t)16 * 32 * 4096;
    unsigned short* weffT  = (unsigned short*)(attnT + (size_t)32 * 4096);
    unsigned short* wfoldT = weffT + (size_t)2 * 1024 * 1024;

    cvt_all_kernel<<<18432, 256, 0, stream>>>(x, Wv, Wqk, xb, wvb, wqkT);

    // qkT = Wqk^T @ x^T: C[c][n], M=1024 (4 m-blks), N=16384 (64 n-blks).
    // swapBig=1: each XCD owns 8 contiguous n-blocks (token range); the 4
    // m-blocks per n-strip are adjacent in dispatch order (share B strip).
    gemm256_bt<1><<<256, 512, 0, stream>>>(
        wqkT, xb, (void*)qkT, 1024, 1024, 1024, 16384, 0, 0, 0, 4, 8, 1);

    gram_kernel<<<dim3(32, 16), 256, 0, stream>>>(qkT, partial);
    softmax_kernel<<<512, 256, 0, stream>>>(partial, tau, attnT);
    wefft_kernel<<<dim3(32, 16), 256, 0, stream>>>(attnT, Wout, weffT);

    // WfoldT_b[j][c'] = sum_i WeffT_b[j][i] * W_v[c'][i]: small, keep 128^2
    gemm_bt<1><<<128, 256, 0, stream>>>(
        weffT, wvb, (void*)wfoldT, 1024, 1024, 1024, 1024,
        (size_t)1024 * 1024, 0, (size_t)1024 * 1024, 8, 1);

    // out_b = x_b @ Wfold_b  (M=8192/z, N=1024, K=1024): 32 m x 4 n x 2 z = 256
    gemm256_bt<0><<<256, 512, 0, stream>>>(
        xb, wfoldT, d_out, 1024, 1024, 1024, 1024,
        (size_t)8192 * 1024, (size_t)1024 * 1024, (size_t)8192 * 1024, 4, 4, 0);
}